// Round 1
// baseline (44.784 us; speedup 1.0000x reference)
//
#include <hip/hip_runtime.h>
#include <math.h>

// CGP elementwise DAG: 4,194,304 rows x 8 f32 in -> 8 f32 out.
// Memory-bound: 256 MiB total traffic, roofline ~43 us @ 6.3 TB/s.
// One row per thread: row = 32 B contiguous -> 2x dwordx4 load + 2x dwordx4 store.

__global__ __launch_bounds__(256) void CGPLayer_60773787239141_kernel(
    const float* __restrict__ x,
    const float* __restrict__ ephs,
    float* __restrict__ out,
    int batch)
{
    const float c0 = ephs[0];
    const float c1 = ephs[1];
    const float c2 = ephs[2];
    const float c3 = ephs[3];

    int tid    = blockIdx.x * blockDim.x + threadIdx.x;
    int stride = gridDim.x * blockDim.x;

    for (int row = tid; row < batch; row += stride) {
        const float4* __restrict__ xp =
            reinterpret_cast<const float4*>(x) + (size_t)row * 2;
        float4 a = xp[0];   // x0..x3
        float4 b = xp[1];   // x4..x7

        float n0  = a.x + a.y;          // add
        float n1  = a.z * a.w;          // mul
        float n2  = sinf(b.x);          // sin
        float n3  = tanhf(b.y + c0);    // add -> tanh
        float n4  = n0 * n1;            // mul
        float n5  = n2 + n3;            // add
        float n6  = n4 - n5;            // sub
        float n7  = cosf(n6);           // cos
        float n8  = n0 * c1;            // mul const
        float n9  = n7 + n8;            // add
        float n10 = tanhf(n9);          // tanh
        float n11 = b.z * b.w;          // mul
        float n12 = n11 + c2;           // add const
        float n13 = sinf(n12);          // sin
        float n14 = n10 * n13;          // mul
        float n15 = n14 + c3;           // add const

        float4 o0 = make_float4(n15, n10, n13, n9);
        float4 o1 = make_float4(n4,  n5,  n7,  n12);

        float4* __restrict__ op =
            reinterpret_cast<float4*>(out) + (size_t)row * 2;
        op[0] = o0;
        op[1] = o1;
    }
}

extern "C" void kernel_launch(void* const* d_in, const int* in_sizes, int n_in,
                              void* d_out, int out_size, void* d_ws, size_t ws_size,
                              hipStream_t stream) {
    const float* x    = (const float*)d_in[0];
    const float* ephs = (const float*)d_in[1];
    float* out        = (float*)d_out;
    int batch = in_sizes[0] / 8;   // 4,194,304

    const int block = 256;
    const int grid  = 2048;        // grid-stride, ~8 rows/thread
    hipLaunchKernelGGL(CGPLayer_60773787239141_kernel,
                       dim3(grid), dim3(block), 0, stream,
                       x, ephs, out, batch);
}